// Round 1
// baseline (281.791 us; speedup 1.0000x reference)
//
#include <hip/hip_runtime.h>

// Problem constants (match the reference).
#define NL    48            // layers
#define RNK   8             // lora rank
#define OUT_D 1024
#define IN_D  1024
#define BN    8             // B*N = 4*2
#define OC    8             // o-chunks per (l,bn)
#define OROWS (OUT_D / OC)  // 128 rows per block

// out[bn] = sum_l sum_r sum_i A[l,r,i] * ( sum_o B[l,o,r] * G[l,bn,o,i] )
//
// Stage 1: one block per (l, bn, oc). Each thread owns a 4-float i-slice.
//   acc[r] += B[l,o,r] * g4      (B is wave-uniform -> LDS broadcast)
//   partial = sum_r A[l,r,slice] . acc[r]
//   block-reduce -> partials[bn*(NL*OC) + l*OC + oc]
// Stage 2: deterministic per-bn reduction of the 384 partials.

__global__ void lora_trace_stage1(const float* __restrict__ lora_A,
                                  const float* __restrict__ lora_B,
                                  const float* __restrict__ grad,
                                  float* __restrict__ partials) {
    const int tid = threadIdx.x;          // 0..255
    const int bid = blockIdx.x;           // 0..3071
    const int oc  = bid % OC;
    const int bn  = (bid / OC) % BN;
    const int l   = bid / (OC * BN);
    const int o0  = oc * OROWS;

    __shared__ float sB[OROWS * RNK];     // 4 KB: B[l, o0..o0+127, 0..7]
    {
        const float* Bsrc = lora_B + (size_t)l * OUT_D * RNK + (size_t)o0 * RNK;
        for (int k = tid; k < OROWS * RNK; k += 256) sB[k] = Bsrc[k];
    }
    __syncthreads();

    const float4* G4 =
        (const float4*)(grad + ((size_t)(l * BN + bn) * OUT_D + (size_t)o0) * IN_D);

    float4 acc[RNK];
    #pragma unroll
    for (int r = 0; r < RNK; ++r) acc[r] = make_float4(0.f, 0.f, 0.f, 0.f);

    #pragma unroll 2
    for (int o = 0; o < OROWS; ++o) {
        float4 g = G4[(size_t)o * (IN_D / 4) + tid];   // coalesced: 64 lanes x 16B
        #pragma unroll
        for (int r = 0; r < RNK; ++r) {
            const float b = sB[o * RNK + r];           // broadcast read
            acc[r].x = fmaf(b, g.x, acc[r].x);
            acc[r].y = fmaf(b, g.y, acc[r].y);
            acc[r].z = fmaf(b, g.z, acc[r].z);
            acc[r].w = fmaf(b, g.w, acc[r].w);
        }
    }

    // Contract the accumulated (r, i-slice) block with A[l].
    float partial = 0.f;
    const float4* A4 = (const float4*)(lora_A + (size_t)l * RNK * IN_D);
    #pragma unroll
    for (int r = 0; r < RNK; ++r) {
        float4 a = A4[r * (IN_D / 4) + tid];
        partial += a.x * acc[r].x + a.y * acc[r].y + a.z * acc[r].z + a.w * acc[r].w;
    }

    // Block reduction: wave (64-lane) shuffle tree, then LDS across 4 waves.
    #pragma unroll
    for (int off = 32; off > 0; off >>= 1)
        partial += __shfl_down(partial, off, 64);

    __shared__ float sP[4];
    const int wid  = tid >> 6;
    const int lane = tid & 63;
    if (lane == 0) sP[wid] = partial;
    __syncthreads();
    if (tid == 0) {
        partials[(size_t)bn * (NL * OC) + (size_t)l * OC + oc] =
            sP[0] + sP[1] + sP[2] + sP[3];
    }
}

__global__ void lora_trace_stage2(const float* __restrict__ partials,
                                  float* __restrict__ out) {
    const int bn  = blockIdx.x;   // 0..7
    const int tid = threadIdx.x;  // 0..63
    float s = 0.f;
    for (int k = tid; k < NL * OC; k += 64)
        s += partials[(size_t)bn * (NL * OC) + k];
    #pragma unroll
    for (int off = 32; off > 0; off >>= 1)
        s += __shfl_down(s, off, 64);
    if (tid == 0) out[bn] = s;
}

extern "C" void kernel_launch(void* const* d_in, const int* in_sizes, int n_in,
                              void* d_out, int out_size, void* d_ws, size_t ws_size,
                              hipStream_t stream) {
    const float* lora_A = (const float*)d_in[0];   // [48, 8, 1024]
    const float* lora_B = (const float*)d_in[1];   // [48, 1024, 8]
    const float* grad   = (const float*)d_in[2];   // [48, 4, 2, 1024, 1024]
    float* out      = (float*)d_out;               // [4, 2] flat = 8 floats
    float* partials = (float*)d_ws;                // 3072 floats = 12 KB

    lora_trace_stage1<<<dim3(NL * BN * OC), dim3(256), 0, stream>>>(
        lora_A, lora_B, grad, partials);
    lora_trace_stage2<<<dim3(BN), dim3(64), 0, stream>>>(partials, out);
}

// Round 3
// 242.650 us; speedup vs baseline: 1.1613x; 1.1613x over previous
//
#include <hip/hip_runtime.h>

// Problem constants (match the reference).
#define NL    48            // layers
#define RNK   8             // lora rank
#define OUT_D 1024
#define IN_D  1024
#define BN    8             // B*N = 4*2
#define OC    8             // o-chunks per (l,bn)
#define OROWS (OUT_D / OC)  // 128 rows per block

typedef float f32x4 __attribute__((ext_vector_type(4)));  // native vector for nt-load

// out[bn] = sum_l sum_r sum_i A[l,r,i] * ( sum_o B[l,o,r] * G[l,bn,o,i] )
//
// Stage 1: one block per (l, bn, oc). Each thread owns a 4-float i-slice.
//   acc[r] += B[l,o,r] * g4      (B is wave-uniform -> LDS broadcast)
//   partial = sum_r A[l,r,slice] . acc[r]
//   block-reduce -> partials[bn*(NL*OC) + l*OC + oc]
// Stage 2: deterministic per-bn reduction of the 384 partials.
//
// Gradient is streamed exactly once -> nontemporal loads (nt) to skip
// L2/L3 line allocation; unroll 4 for deeper MLP.

__global__ void lora_trace_stage1(const float* __restrict__ lora_A,
                                  const float* __restrict__ lora_B,
                                  const float* __restrict__ grad,
                                  float* __restrict__ partials) {
    const int tid = threadIdx.x;          // 0..255
    const int bid = blockIdx.x;           // 0..3071
    const int oc  = bid % OC;
    const int bn  = (bid / OC) % BN;
    const int l   = bid / (OC * BN);
    const int o0  = oc * OROWS;

    __shared__ float sB[OROWS * RNK];     // 4 KB: B[l, o0..o0+127, 0..7]
    {
        const float* Bsrc = lora_B + (size_t)l * OUT_D * RNK + (size_t)o0 * RNK;
        for (int k = tid; k < OROWS * RNK; k += 256) sB[k] = Bsrc[k];
    }
    __syncthreads();

    const f32x4* G4 =
        (const f32x4*)(grad + ((size_t)(l * BN + bn) * OUT_D + (size_t)o0) * IN_D);

    f32x4 acc[RNK];
    #pragma unroll
    for (int r = 0; r < RNK; ++r) acc[r] = (f32x4)(0.f);

    #pragma unroll 4
    for (int o = 0; o < OROWS; ++o) {
        f32x4 g = __builtin_nontemporal_load(&G4[(size_t)o * (IN_D / 4) + tid]);
        #pragma unroll
        for (int r = 0; r < RNK; ++r) {
            const float b = sB[o * RNK + r];           // broadcast read
            acc[r].x = fmaf(b, g.x, acc[r].x);
            acc[r].y = fmaf(b, g.y, acc[r].y);
            acc[r].z = fmaf(b, g.z, acc[r].z);
            acc[r].w = fmaf(b, g.w, acc[r].w);
        }
    }

    // Contract the accumulated (r, i-slice) block with A[l].
    float partial = 0.f;
    const f32x4* A4 = (const f32x4*)(lora_A + (size_t)l * RNK * IN_D);
    #pragma unroll
    for (int r = 0; r < RNK; ++r) {
        f32x4 a = A4[r * (IN_D / 4) + tid];
        partial += a.x * acc[r].x + a.y * acc[r].y + a.z * acc[r].z + a.w * acc[r].w;
    }

    // Block reduction: wave (64-lane) shuffle tree, then LDS across 4 waves.
    #pragma unroll
    for (int off = 32; off > 0; off >>= 1)
        partial += __shfl_down(partial, off, 64);

    __shared__ float sP[4];
    const int wid  = tid >> 6;
    const int lane = tid & 63;
    if (lane == 0) sP[wid] = partial;
    __syncthreads();
    if (tid == 0) {
        partials[(size_t)bn * (NL * OC) + (size_t)l * OC + oc] =
            sP[0] + sP[1] + sP[2] + sP[3];
    }
}

__global__ void lora_trace_stage2(const float* __restrict__ partials,
                                  float* __restrict__ out) {
    const int bn  = blockIdx.x;   // 0..7
    const int tid = threadIdx.x;  // 0..63
    float s = 0.f;
    for (int k = tid; k < NL * OC; k += 64)
        s += partials[(size_t)bn * (NL * OC) + k];
    #pragma unroll
    for (int off = 32; off > 0; off >>= 1)
        s += __shfl_down(s, off, 64);
    if (tid == 0) out[bn] = s;
}

extern "C" void kernel_launch(void* const* d_in, const int* in_sizes, int n_in,
                              void* d_out, int out_size, void* d_ws, size_t ws_size,
                              hipStream_t stream) {
    const float* lora_A = (const float*)d_in[0];   // [48, 8, 1024]
    const float* lora_B = (const float*)d_in[1];   // [48, 1024, 8]
    const float* grad   = (const float*)d_in[2];   // [48, 4, 2, 1024, 1024]
    float* out      = (float*)d_out;               // [4, 2] flat = 8 floats
    float* partials = (float*)d_ws;                // 3072 floats = 12 KB

    lora_trace_stage1<<<dim3(NL * BN * OC), dim3(256), 0, stream>>>(
        lora_A, lora_B, grad, partials);
    lora_trace_stage2<<<dim3(BN), dim3(64), 0, stream>>>(partials, out);
}